// Round 1
// 269.442 us; speedup vs baseline: 1.0269x; 1.0269x over previous
//
#include <hip/hip_runtime.h>
#include <hip/hip_bf16.h>
#include <cstdint>
#include <cstddef>

#define DIM  128
#define NREL 8
#define SCB  4096   // elements per scan block (16 per thread)
#define CPB  32     // cols per fused block (64 KB LDS, 512-thr blocks -> 2 blocks/CU)

typedef __attribute__((ext_vector_type(8))) short short8;
typedef __attribute__((ext_vector_type(4))) float f32x4;

static inline int cdiv(int a, int b){ return (a + b - 1) / b; }

__device__ inline unsigned short f2bf(float f){
    union { float f; uint32_t u; } v; v.f = f;
    uint32_t u = v.u;
    uint32_t r = (u + 0x7FFFu + ((u >> 16) & 1u)) >> 16;   // RNE
    return (unsigned short)r;
}
__device__ inline uint32_t pack2(float lo, float hi){
    return (uint32_t)f2bf(lo) | ((uint32_t)f2bf(hi) << 16);
}
__device__ inline float bf2f(uint32_t lo16){
    union { uint32_t u; float f; } v; v.u = lo16 << 16; return v.f;
}
__device__ inline float asf(int u){
    union { int i; float f; } v; v.i = u; return v.f;
}

// ---- fused prep: [0,nb4) xb convert | [nb4,nb4+eb) (col,type) histogram | [..,+128) wpk ----
// wpk B-frag for 16x16x32: lane l holds B[k = ks*32 + (l>>4)*8 + j][n = nt*16 + (l&15)]
__global__ __launch_bounds__(256) void k_prep(const float4* __restrict__ x, unsigned short* __restrict__ xb, int n4,
                                              const int* __restrict__ col, const int* __restrict__ et, int E,
                                              int* __restrict__ cnt8, int nb4, int eb,
                                              const float* __restrict__ W1, const float* __restrict__ W2,
                                              unsigned short* __restrict__ wpk){
    int blk = blockIdx.x;
    if (blk < nb4){
        int i = blk * 256 + threadIdx.x;
        if (i >= n4) return;
        float4 v = x[i];
        ushort4 o; o.x = f2bf(v.x); o.y = f2bf(v.y); o.z = f2bf(v.z); o.w = f2bf(v.w);
        *(ushort4*)(xb + (size_t)i * 4) = o;
    } else if (blk < nb4 + eb){
        int e = (blk - nb4) * 256 + threadIdx.x;
        if (e < E) atomicAdd(&cnt8[col[e] * NREL + et[e]], 1);
    } else {
        int b = (blk - nb4 - eb) * 4 + (threadIdx.x >> 6);   // ((slot*8+nt)*4+ks), 512 total
        int lane = threadIdx.x & 63;
        int ks = b & 3, nt = (b >> 2) & 7, slot = b >> 5;
        const float* Wsrc = (slot < 8) ? (W1 + (size_t)slot * DIM * DIM)
                                       : (W2 + (size_t)(slot - 8) * DIM * DIM);
        int k0 = ks * 32 + (lane >> 4) * 8;
        int n  = nt * 16 + (lane & 15);
        unsigned short o[8];
        #pragma unroll
        for (int j = 0; j < 8; ++j) o[j] = f2bf(Wsrc[(size_t)(k0 + j) * DIM + n]);
        unsigned short* dst = wpk + ((size_t)b * 64 + lane) * 8;
        #pragma unroll
        for (int j = 0; j < 8; ++j) dst[j] = o[j];
    }
}

// ---- colCnt[c] = sum_t cnt8[c*8+t] (degree for normalization) ----
__global__ __launch_bounds__(256) void k_colsum(const int* __restrict__ cnt8, int N, int* __restrict__ colCnt){
    int c = blockIdx.x * 256 + threadIdx.x;
    if (c >= N) return;
    int s = 0;
    #pragma unroll
    for (int t = 0; t < NREL; ++t) s += cnt8[c * NREL + t];
    colCnt[c] = s;
}

// ---- hierarchical exclusive scan of cnt8 (M8 = N*8) -> start8[M8+1], pos8 ----
__global__ __launch_bounds__(256) void k_scan1(const int* __restrict__ cnt, int M, int* __restrict__ bsum){
    int t = threadIdx.x;
    int base = blockIdx.x * SCB + t * 16;
    int s = 0;
    #pragma unroll
    for (int k = 0; k < 16; ++k){
        int i = base + k;
        if (i < M) s += cnt[i];
    }
    #pragma unroll
    for (int o = 1; o < 64; o <<= 1) s += __shfl_xor(s, o);
    __shared__ int wsum[4];
    if ((t & 63) == 0) wsum[t >> 6] = s;
    __syncthreads();
    if (t == 0) bsum[blockIdx.x] = wsum[0] + wsum[1] + wsum[2] + wsum[3];
}

// single wave, 8 entries/lane: parallel exclusive scan of up to 512 block sums
__global__ void k_scan2(int* __restrict__ bsum, int NBS, int* __restrict__ total){
    int lane = threadIdx.x & 63;
    int v[8]; int s = 0; int base = lane * 8;
    #pragma unroll
    for (int k = 0; k < 8; ++k){ int i = base + k; v[k] = (i < NBS) ? bsum[i] : 0; s += v[k]; }
    int inc = s;
    #pragma unroll
    for (int o = 1; o < 64; o <<= 1){ int u = __shfl_up(inc, o); if (lane >= o) inc += u; }
    int excl = inc - s;
    #pragma unroll
    for (int k = 0; k < 8; ++k){ int i = base + k; if (i < NBS) bsum[i] = excl; excl += v[k]; }
    if (lane == 63) *total = inc;
}

__global__ __launch_bounds__(256) void k_scan3(const int* __restrict__ cnt, int M,
                                               const int* __restrict__ bsum, const int* __restrict__ total,
                                               int* __restrict__ startArr, int* __restrict__ pos){
    int t = threadIdx.x;
    int base = blockIdx.x * SCB + t * 16;
    int vals[16];
    int s = 0;
    #pragma unroll
    for (int k = 0; k < 16; ++k){
        int i = base + k;
        vals[k] = (i < M) ? cnt[i] : 0;
        s += vals[k];
    }
    int lane = t & 63, w = t >> 6;
    int v = s;
    #pragma unroll
    for (int o = 1; o < 64; o <<= 1){
        int u = __shfl_up(v, o);
        if (lane >= o) v += u;
    }
    __shared__ int wsum[4];
    if (lane == 63) wsum[w] = v;
    __syncthreads();
    int excl = v - s + bsum[blockIdx.x];
    for (int i = 0; i < w; ++i) excl += wsum[i];
    #pragma unroll
    for (int k = 0; k < 16; ++k){
        int i = base + k;
        if (i < M){ startArr[i] = excl; pos[i] = excl; excl += vals[k]; }
    }
    if (blockIdx.x == 0 && t == 0) startArr[M] = *total;
}

// ---- place edges sorted by (col,type); coef inline; meta {cl<<24 | row<<3 | type, coef} ----
__global__ __launch_bounds__(256) void k_place(const int* __restrict__ row, const int* __restrict__ col,
                                               const int* __restrict__ et, const float* __restrict__ ew,
                                               const int* __restrict__ colCnt,
                                               int E, int* __restrict__ pos8, int2* __restrict__ pkm){
    int e = blockIdx.x * 256 + threadIdx.x;
    if (e >= E) return;
    int r = row[e], c = col[e], t = et[e];
    int dr = colCnt[r], dc = colCnt[c];
    float a = dr > 0 ? rsqrtf((float)dr) : 0.f;
    float b = dc > 0 ? rsqrtf((float)dc) : 0.f;
    float cf = a * b * ew[e];
    int p = atomicAdd(&pos8[c * NREL + t], 1);
    union { float f; int i; } cv; cv.f = cf;
    pkm[p] = make_int2(((c & (CPB - 1)) << 24) | (r << 3) | t, cv.i);
}

// ---- fused aggregate + transform conv ----
// out[c] = bias + sum_t ( sum_{e: col=c, type=t} coef_e * x[row_e] ) @ W[t]
// 512 threads = 8 waves; block owns 32 cols.
// Phase 1: wave owns 4 cols, contiguous (col,type)-sorted edge range; metas 64-at-a-time
//   coalesced -> v_readlane; row gathers batched 8 deep; run-segmented acc in 2 regs ->
//   swizzled bf16 A-tile ds_write per (col,type) run.
// Phase 2: K-SPLIT wave grid: wave = (kh = wid>>2, np = wid&3).
//   Wave tile M=32 x N=32 (n-tiles 2np,2np+1) x K=512 (relations kh*4..kh*4+3).
//   Each A frag feeds 2 MFMAs, each B frag belongs to exactly one wave ->
//   per-col LDS-A traffic AND per-col L2-B traffic both halved vs CPB=16.
// Reduce: fp32 partials [2][32][128] in LDS (reusing A-tile space), epilogue sums halves.
template<int MODE>
__global__ __launch_bounds__(512, 4) void k_fused(const unsigned short* __restrict__ xbin,
                                                  const unsigned short* __restrict__ wpk,
                                                  const int* __restrict__ cs8,
                                                  const int2* __restrict__ pkm,
                                                  const float* __restrict__ bias,
                                                  unsigned short* __restrict__ zb,
                                                  const unsigned short* __restrict__ xb2,
                                                  const unsigned short* __restrict__ z1b2,
                                                  float* __restrict__ outS,
                                                  float* __restrict__ outH,
                                                  int N, int wslot){
    __shared__ unsigned short s[CPB * 1024];    // 64 KB: bf16 A-tile, then fp32 partial tile
    int tid = threadIdx.x;
    int wid = tid >> 6, lane = tid & 63;
    int c0 = blockIdx.x * CPB;

    // zero the A-tile (4096 uint4 / 512 threads)
    uint4 z4 = {0u, 0u, 0u, 0u};
    #pragma unroll
    for (int k = 0; k < 8; ++k) ((uint4*)s)[tid + 512 * k] = z4;
    __syncthreads();

#define FLUSH() *(uint32_t*)((char*)s + flushByte) = pack2(a0, a1)
#define PROC(rt, cf, u) do{                                                       \
        int fk_ = (rt) & 0xFF000007;                                              \
        if (fk_ != fkPrev){                                                       \
            if (fkPrev >= 0) FLUSH();                                             \
            fkPrev = fk_;                                                         \
            int cl_ = ((unsigned)(rt)) >> 24; int t_ = (rt) & 7;                  \
            flushByte = cl_ * 2048 + (((t_ << 8) | (lane << 2)) ^ ((cl_ & 7) << 4)); \
            a0 = 0.f; a1 = 0.f;                                                   \
        }                                                                         \
        a0 = fmaf(cf, bf2f((u) & 0xFFFFu), a0);                                   \
        a1 = fmaf(cf, bf2f((u) >> 16),     a1); }while(0)
#define XROW(mx) ((const uint32_t*)(xbin + ((size_t)(((mx) >> 3) & 0x1FFFFF) << 7)))[lane]

    // ---- phase 1: 4 cols per wave, one contiguous edge range ----
    {
        int c = c0 + wid * 4;
        if (c < N){
            int cHi = c + 4; if (cHi > N) cHi = N;
            int e  = cs8[c * NREL];
            int eE = cs8[cHi * NREL];
            int fkPrev = -1;
            int flushByte = 0;
            float a0 = 0.f, a1 = 0.f;
            while (e < eE){
                int n = eE - e; if (n > 64) n = 64;
                int li = lane < n ? lane : n - 1;
                int2 mv = pkm[e + li];            // 64 metas, one coalesced load
                int j = 0;
                for (; j + 8 <= n; j += 8){
                    int rt[8]; float cf[8]; uint32_t u[8];
                    #pragma unroll
                    for (int k = 0; k < 8; ++k){
                        rt[k] = __builtin_amdgcn_readlane(mv.x, j + k);
                        cf[k] = asf(__builtin_amdgcn_readlane(mv.y, j + k));
                    }
                    #pragma unroll
                    for (int k = 0; k < 8; ++k) u[k] = XROW(rt[k]);
                    #pragma unroll
                    for (int k = 0; k < 8; ++k) PROC(rt[k], cf[k], u[k]);
                }
                for (; j < n; ++j){
                    int rt = __builtin_amdgcn_readlane(mv.x, j);
                    float cf = asf(__builtin_amdgcn_readlane(mv.y, j));
                    uint32_t u = XROW(rt);
                    PROC(rt, cf, u);
                }
                e += n;
            }
            if (fkPrev >= 0) FLUSH();
        }
    }
#undef PROC
#undef FLUSH
#undef XROW
    __syncthreads();

    // ---- phase 2: wave (kh,np): M=32, N=32 (nt = 2np, 2np+1), K=512 (t = kh*4 .. kh*4+3) ----
    int kh = wid >> 2, np = wid & 3;
    f32x4 acc00 = {0,0,0,0}, acc01 = {0,0,0,0}, acc10 = {0,0,0,0}, acc11 = {0,0,0,0};

    int al = lane & 15, ak2 = (lane >> 4) * 16;
    int swz = (al & 7) << 4;
    const char* rowA0 = (const char*)s + al * 2048;         // M-tile 0: rows 0..15
    const char* rowA1 = rowA0 + 16 * 2048;                  // M-tile 1: rows 16..31

    const short8* bb = (const short8*)wpk + (size_t)(wslot + kh * 4) * 2048 + lane;
    const short8* b0 = bb + np * 512;   // nt0 = 2np   -> (nt0*4)*64 = np*512
    const short8* b1 = b0 + 256;        // nt1 = 2np+1

    #pragma unroll 4
    for (int ksg = 0; ksg < 16; ++ksg){
        int off = (((kh * 16 + ksg) * 64) + ak2) ^ swz;
        short8 A0 = *(const short8*)(rowA0 + off);
        short8 A1 = *(const short8*)(rowA1 + off);
        int bidx = (ksg >> 2) * 2048 + (ksg & 3) * 64;      // t-step*2048 + ksl*64
        short8 B0 = b0[bidx];
        short8 B1 = b1[bidx];
        acc00 = __builtin_amdgcn_mfma_f32_16x16x32_bf16(A0, B0, acc00, 0, 0, 0);
        acc01 = __builtin_amdgcn_mfma_f32_16x16x32_bf16(A0, B1, acc01, 0, 0, 0);
        acc10 = __builtin_amdgcn_mfma_f32_16x16x32_bf16(A1, B0, acc10, 0, 0, 0);
        acc11 = __builtin_amdgcn_mfma_f32_16x16x32_bf16(A1, B1, acc11, 0, 0, 0);
    }
    __syncthreads();   // all A-reads done; reuse s as fp32 partial tile [2][32][128]

    // ---- write K-half partials to LDS ----
    float* ot = (float*)s;
    {
        int crb = (lane >> 4) * 4, dcl = lane & 15;
        int d0 = np * 32 + dcl;                     // nt0*16 + dcl
        float* base0 = ot + kh * 4096 + crb * 128;
        #pragma unroll
        for (int r = 0; r < 4; ++r){
            base0[r * 128 + d0]               = acc00[r];
            base0[r * 128 + d0 + 16]          = acc01[r];
            base0[(16 * 128) + r * 128 + d0]      = acc10[r];
            base0[(16 * 128) + r * 128 + d0 + 16] = acc11[r];
        }
    }
    __syncthreads();

    // ---- epilogue: sum the two K-halves + bias; coalesced output ----
    {
        int rowi = tid >> 4, seg = tid & 15;
        int c = c0 + rowi;
        if (c < N){
            int d0 = seg * 8;
            const float* s0 = ot + rowi * DIM + d0;
            const float* s1 = s0 + 4096;
            float v[8];
            #pragma unroll
            for (int j = 0; j < 8; ++j) v[j] = s0[j] + s1[j] + bias[d0 + j];
            if (MODE == 0){
                #pragma unroll
                for (int j = 0; j < 8; ++j) v[j] = fmaxf(v[j], 0.f);
                uint4 vv;
                vv.x = pack2(v[0], v[1]);
                vv.y = pack2(v[2], v[3]);
                vv.z = pack2(v[4], v[5]);
                vv.w = pack2(v[6], v[7]);
                *(uint4*)(zb + ((size_t)c << 7) + d0) = vv;
            } else {
                size_t o = ((size_t)c << 7) + d0;
                uint4 xu = *(const uint4*)(xb2 + o);
                uint4 zu = *(const uint4*)(z1b2 + o);
                uint32_t xw[4] = {xu.x, xu.y, xu.z, xu.w};
                uint32_t zw[4] = {zu.x, zu.y, zu.z, zu.w};
                float S[8], H[8];
                #pragma unroll
                for (int j = 0; j < 4; ++j){
                    float x0 = bf2f(xw[j] & 0xFFFFu), x1 = bf2f(xw[j] >> 16);
                    float z0 = bf2f(zw[j] & 0xFFFFu), z1 = bf2f(zw[j] >> 16);
                    S[2*j]   = (x0 + z0 + v[2*j])   * 0.25f;
                    S[2*j+1] = (x1 + z1 + v[2*j+1]) * 0.25f;
                    H[2*j]   = (z0 + v[2*j])   * (1.0f / 3.0f);
                    H[2*j+1] = (z1 + v[2*j+1]) * (1.0f / 3.0f);
                }
                f32x4 S0 = {S[0], S[1], S[2], S[3]}, S1 = {S[4], S[5], S[6], S[7]};
                f32x4 H0 = {H[0], H[1], H[2], H[3]}, H1 = {H[4], H[5], H[6], H[7]};
                __builtin_nontemporal_store(S0, (f32x4*)(outS + o));
                __builtin_nontemporal_store(S1, (f32x4*)(outS + o + 4));
                __builtin_nontemporal_store(H0, (f32x4*)(outH + o));
                __builtin_nontemporal_store(H1, (f32x4*)(outH + o + 4));
            }
        }
    }
}

extern "C" void kernel_launch(void* const* d_in, const int* in_sizes, int n_in,
                              void* d_out, int out_size, void* d_ws, size_t ws_size,
                              hipStream_t stream) {
    const float* x  = (const float*)d_in[0];
    const int*   ei = (const int*)d_in[1];
    const int*   et = (const int*)d_in[2];
    const float* ew = (const float*)d_in[3];
    const float* W1 = (const float*)d_in[4];
    const float* b1 = (const float*)d_in[5];
    const float* W2 = (const float*)d_in[6];
    const float* b2 = (const float*)d_in[7];

    int E = in_sizes[2];
    int N = in_sizes[0] / DIM;
    const int* row = ei;
    const int* col = ei + E;

    float* out = (float*)d_out;
    int ND  = N * DIM;
    int ND4 = ND / 4;
    float* zS = out;        // slot 0: z_star
    float* zH = out + ND;   // slot 1: z_sharp

    int M8   = N * NREL;
    int NBS8 = cdiv(M8, SCB);

    // ---- workspace carve (~70 MB) ----
    char* wsb = (char*)d_ws;
    size_t off = 0;
    auto take = [&](size_t bytes) -> char* {
        char* p = wsb + off;
        off = (off + bytes + 255) & ~(size_t)255;
        return p;
    };
    int*            cnt8     = (int*)           take((size_t)M8 * 4);
    int*            start8   = (int*)           take(((size_t)M8 + 1) * 4);
    int*            pos8     = (int*)           take((size_t)M8 * 4);
    int*            colCnt   = (int*)           take((size_t)N * 4);
    int*            bsum     = (int*)           take(((size_t)NBS8 + 1) * 4);
    int2*           pkm      = (int2*)          take((size_t)E * 8);
    unsigned short* wpk      = (unsigned short*)take((size_t)16 * 2048 * 8 * 2);   // 512 KB
    unsigned short* xb       = (unsigned short*)take((size_t)ND * 2);
    unsigned short* z1b      = (unsigned short*)take((size_t)ND * 2);
    int* total = bsum + NBS8;
    (void)n_in; (void)out_size; (void)ws_size;

    hipMemsetAsync(cnt8, 0, (size_t)M8 * 4, stream);

    int eb  = cdiv(E, 256);
    int nb4 = cdiv(ND4, 256);
    int nb  = cdiv(N, 256);
    k_prep  <<<nb4 + eb + 128, 256, 0, stream>>>((const float4*)x, xb, ND4, col, et, E, cnt8, nb4, eb, W1, W2, wpk);
    k_colsum<<<nb, 256, 0, stream>>>(cnt8, N, colCnt);
    k_scan1 <<<NBS8, 256, 0, stream>>>(cnt8, M8, bsum);
    k_scan2 <<<1, 64, 0, stream>>>(bsum, NBS8, total);
    k_scan3 <<<NBS8, 256, 0, stream>>>(cnt8, M8, bsum, total, start8, pos8);
    k_place <<<eb, 256, 0, stream>>>(row, col, et, ew, colCnt, E, pos8, pkm);

    int fb = cdiv(N, CPB);
    // conv1: z1b = bf16(relu(agg(x) @ W1 + b1))
    k_fused<0><<<fb, 512, 0, stream>>>(xb, wpk, start8, pkm, b1, z1b, nullptr, nullptr, nullptr, nullptr, N, 0);
    // conv2: fused z_star/z_sharp from xb, z1b, agg(z1b) @ W2 + b2
    k_fused<1><<<fb, 512, 0, stream>>>(z1b, wpk, start8, pkm, b2, nullptr, xb, z1b, zS, zH, N, 8);
}